// Round 8
// baseline (304.595 us; speedup 1.0000x reference)
//
#include <hip/hip_runtime.h>
#include <stdint.h>

// SparseAttention MI355X bf16-MFMA pipeline. Output f32.
// R19: attn restructured 4-wave/16-rows -> 2-wave/32-rows (2 m-frags/wave).
// Diagnosis: attn is LDS-throughput-bound (~1250 DS-cyc/tile-unit; MFMA only
// ~5%). K/V fragments were read 4x (identical across waves); 2-wave blocks
// read them 2x and reuse across m-frags (b128/tile-unit 88->56, ~10us/CU).
// Block=128thr, grid 2560, LDS 24KB -> 6 blk/CU; launch_bounds(128,2)
// (256-reg budget, est ~160 live; spill alarm = WRITE_SIZE).
// kF loaded once per nt, both mf MFMAs consume; per-nt mask+exp+P-write
// keeps transients small. pk[4]/pv[4] prefetch statically indexed.
// R18 (kept): qkv V-panels write Vtb from acc; vprep gather-only; GEMM
// counted-vmcnt dbuf loop. attn swizzle verified 0-conflict.
// MFMA 16x16x32 bf16 layouts (HW-verified): A[m=lane&15][k=quad*8+j],
// B[k=quad*8+j][n=lane&15], C/D col=lane&15 row=quad*4+reg.

#define NH 12
#define SQ 2048

typedef __bf16 bf16x8 __attribute__((ext_vector_type(8)));
typedef float f32x4 __attribute__((ext_vector_type(4)));

#define GLOAD_LDS16(g, l)                                                      \
  __builtin_amdgcn_global_load_lds(                                            \
      (__attribute__((address_space(1))) void*)(g),                            \
      (__attribute__((address_space(3))) void*)(l), 16, 0, 0)

__device__ __forceinline__ unsigned short bfbits(float f) {
  __bf16 h = (__bf16)f;
  return *(unsigned short*)&h;
}

// ---------------- prep: x->bf16 + both weight transposes (1 kernel) --------
__global__ __launch_bounds__(256) void prep(
    const float* __restrict__ x, unsigned short* __restrict__ xb,
    const float* __restrict__ w_attn, unsigned short* __restrict__ wattnT,
    const float* __restrict__ w_proj, unsigned short* __restrict__ wprojT) {
  const int bid = blockIdx.x, t = threadIdx.x;
  if (bid < 512) {                 // convert x: 8192*768 floats
    const int n4 = 8192 * 768 / 4;
    for (int i = bid * 256 + t; i < n4; i += 512 * 256) {
      float4 v = ((const float4*)x)[i];
      ((ushort4*)xb)[i] = make_ushort4(bfbits(v.x), bfbits(v.y), bfbits(v.z), bfbits(v.w));
    }
    return;
  }
  __shared__ float tile[32][33];
  const float* in; unsigned short* out; int K, N, tl;
  if (bid < 512 + 72 * 24) { in = w_attn; out = wattnT; K = 768; N = 2304; tl = bid - 512; }
  else                     { in = w_proj; out = wprojT; K = 768; N = 768;  tl = bid - 512 - 72 * 24; }
  const int tpr = N / 32;
  const int n0 = (tl % tpr) * 32, k0 = (tl / tpr) * 32;
  const int tx = t & 31, ty = t >> 5;
  for (int r = ty; r < 32; r += 8) tile[r][tx] = in[(size_t)(k0 + r) * N + n0 + tx];
  __syncthreads();
  for (int r = ty; r < 32; r += 8) out[(size_t)(n0 + r) * K + k0 + tx] = bfbits(tile[tx][r]);
}

// ---------------- vprep: gcol gather only (V transpose now in qkv) ---------
__global__ __launch_bounds__(256) void vprep(const unsigned short* __restrict__ QKV,
                                             const unsigned short* __restrict__ Vtb,
                                             unsigned short* __restrict__ Kg,
                                             unsigned short* __restrict__ VgT,
                                             int* __restrict__ gidx) {
  const int g = blockIdx.x, t = threadIdx.x;   // 128 = 16 bh * 8 chunks
  const int bh = g >> 3, y = g & 7;
  const int b = bh >> 2, h = 8 + (bh & 3);
  const int bh48 = b * NH + h;
  if (g == 0) {
    int c = t;
    gidx[c] = (c < 203) ? (int)((double)c * (2047.0 / 203.0)) : ((c == 203) ? 2047 : -1);
  }
  {  // Kg rows from qkvb K-section
    int c = t, ch = y;
    int col = (c < 203) ? (int)((double)c * (2047.0 / 203.0)) : ((c == 203) ? 2047 : -1);
    uint4 v = {0u, 0u, 0u, 0u};
    if (col >= 0) v = *(const uint4*)&QKV[(size_t)(b * SQ + col) * 2304 + 768 + h * 64 + ch * 8];
    *(uint4*)&Kg[((size_t)bh * 256 + c) * 64 + ch * 8] = v;
  }
  {  // VgT gathered from Vtb (written by qkv_gemm V-panels)
    int d = t >> 2;
    int cb = (t & 3) * 64 + y * 8;
    for (int cc = 0; cc < 8; ++cc) {
      int c = cb + cc;
      int col = (c < 203) ? (int)((double)c * (2047.0 / 203.0)) : ((c == 203) ? 2047 : -1);
      unsigned short v = 0;
      if (col >= 0) v = Vtb[(size_t)bh48 * 131072 + (size_t)d * 2048 + col];
      VgT[((size_t)bh * 64 + d) * 256 + c] = v;
    }
  }
}

// ---- GEMM mainloop: 128x128, BK=64, dbuf, counted vmcnt, raw barriers -----
__device__ __forceinline__ void gemm_mainloop(
    const unsigned short* __restrict__ A, const unsigned short* __restrict__ BT,
    int m0, int n0, int tid,
    unsigned short* As, unsigned short* Bs,    // each 2*128*64 u16
    f32x4 acc[4][4]) {
  const int lane = tid & 63, wave = tid >> 6;
  const int wm = wave >> 1, wn = wave & 1;
  const int ln = lane & 15, quad = lane >> 4, ln7 = lane & 7;
  const int srow = tid >> 3;                        // 0..31 (+rr*32)
  const int scol = ((tid & 7) ^ (srow & 7)) * 8;    // pre-swizzled source slot
  const int sbase = wave * 512;                     // u16; lane adds lane*8

#pragma unroll
  for (int mi = 0; mi < 4; ++mi)
#pragma unroll
    for (int ni = 0; ni < 4; ++ni) acc[mi][ni] = (f32x4){0.f, 0.f, 0.f, 0.f};

  auto stage = [&](int kt, int buf) {
    const int k0 = kt * 64;
    const int bo = buf * 8192;
#pragma unroll
    for (int rr = 0; rr < 4; ++rr) {
      GLOAD_LDS16(A  + (size_t)(m0 + rr * 32 + srow) * 768 + k0 + scol,
                  &As[bo + rr * 2048 + sbase]);
      GLOAD_LDS16(BT + (size_t)(n0 + rr * 32 + srow) * 768 + k0 + scol,
                  &Bs[bo + rr * 2048 + sbase]);
    }
  };

  stage(0, 0);
  int buf = 0;
  for (int kt = 0; kt < 12; ++kt) {
    if (kt < 11) {
      stage(kt + 1, buf ^ 1);   // next tile's 8 loads issued first
      asm volatile("s_waitcnt vmcnt(8)" ::: "memory");  // tile-t landed; 8 in flight
    } else {
      asm volatile("s_waitcnt vmcnt(0)" ::: "memory");  // last tile: drain
    }
    __builtin_amdgcn_sched_barrier(0);
    __builtin_amdgcn_s_barrier();                     // publish staged tile
    const int bo = buf * 8192;
#pragma unroll
    for (int kh = 0; kh < 2; ++kh) {
      const int sk = ((kh * 4 + quad) ^ ln7) * 8;
      bf16x8 aF[4], bF[4];
#pragma unroll
      for (int mi = 0; mi < 4; ++mi)
        aF[mi] = *(const bf16x8*)&As[bo + (wm * 64 + mi * 16 + ln) * 64 + sk];
#pragma unroll
      for (int ni = 0; ni < 4; ++ni)
        bF[ni] = *(const bf16x8*)&Bs[bo + (wn * 64 + ni * 16 + ln) * 64 + sk];
#pragma unroll
      for (int mi = 0; mi < 4; ++mi)
#pragma unroll
        for (int ni = 0; ni < 4; ++ni)
          acc[mi][ni] = __builtin_amdgcn_mfma_f32_16x16x32_bf16(aF[mi], bF[ni], acc[mi][ni], 0, 0, 0);
    }
    asm volatile("s_waitcnt lgkmcnt(0)" ::: "memory"); // all LDS reads done
    __builtin_amdgcn_sched_barrier(0);
    __builtin_amdgcn_s_barrier();                      // safe to overwrite buf
    buf ^= 1;
  }
}

// ---------------- QKV GEMM: Q/K -> qkvb row-major; V -> Vtb transposed -----
__global__ __launch_bounds__(256, 2) void qkv_gemm(
    const unsigned short* __restrict__ Xb, const unsigned short* __restrict__ WT,
    const float* __restrict__ bias, unsigned short* __restrict__ Out,
    unsigned short* __restrict__ Vtb) {
  __shared__ __attribute__((aligned(16))) unsigned short As[2 * 128 * 64];
  __shared__ __attribute__((aligned(16))) unsigned short Bs[2 * 128 * 64];
  f32x4 acc[4][4];
  // 1152 blocks (64 m x 18 n), 1152%8==0: chunked bijective XCD swizzle.
  const int wg = (blockIdx.x & 7) * 144 + (blockIdx.x >> 3);
  const int m0 = (wg / 18) * 128, n0 = (wg % 18) * 128;
  const int tid = threadIdx.x;
  gemm_mainloop(Xb, WT, m0, n0, tid, As, Bs, acc);
  const int lane = tid & 63, wave = tid >> 6;
  const int wm = wave >> 1, wn = wave & 1, ln = lane & 15, quad = lane >> 4;
  if (n0 < 1536) {   // Q/K panels: row-major bf16 qkvb
#pragma unroll
    for (int mi = 0; mi < 4; ++mi)
#pragma unroll
      for (int ni = 0; ni < 4; ++ni) {
        int n = n0 + wn * 64 + ni * 16 + ln;
        float bs = bias[n];
#pragma unroll
        for (int rg = 0; rg < 4; ++rg) {
          int m = m0 + wm * 64 + mi * 16 + quad * 4 + rg;
          Out[(size_t)m * 2304 + n] = bfbits(acc[mi][ni][rg] + bs);
        }
      }
  } else {           // V panels: write Vtb[bh48][d][key] directly from acc
    const int bb = m0 >> 11;                 // batch (128 | 2048)
    const int key0 = (m0 & 2047) + wm * 64;  // + mi*16 + quad*4 + rg
#pragma unroll
    for (int ni = 0; ni < 4; ++ni) {
      int e = (n0 - 1536) + wn * 64 + ni * 16 + ln;   // 0..767
      int h = e >> 6, d = e & 63;
      float bs = bias[1536 + e];
      size_t rowb = (size_t)(bb * NH + h) * 131072 + (size_t)d * 2048;
#pragma unroll
      for (int mi = 0; mi < 4; ++mi) {
        int key = key0 + mi * 16 + quad * 4;
        unsigned int w0 = (unsigned int)bfbits(acc[mi][ni][0] + bs) |
                          ((unsigned int)bfbits(acc[mi][ni][1] + bs) << 16);
        unsigned int w1 = (unsigned int)bfbits(acc[mi][ni][2] + bs) |
                          ((unsigned int)bfbits(acc[mi][ni][3] + bs) << 16);
        *(unsigned int*)&Vtb[rowb + key]     = w0;   // keys key..key+1
        *(unsigned int*)&Vtb[rowb + key + 2] = w1;   // keys key+2..key+3
      }
    }
  }
}

// ---------------- Proj GEMM: fp32 out (XCD-swizzled 1D grid) ---------------
__global__ __launch_bounds__(256, 2) void proj_gemm(
    const unsigned short* __restrict__ Ab, const unsigned short* __restrict__ WT,
    const float* __restrict__ bias, float* __restrict__ Out) {
  __shared__ __attribute__((aligned(16))) unsigned short As[2 * 128 * 64];
  __shared__ __attribute__((aligned(16))) unsigned short Bs[2 * 128 * 64];
  f32x4 acc[4][4];
  // 384 blocks (64 m x 6 n), 384%8==0.
  const int wg = (blockIdx.x & 7) * 48 + (blockIdx.x >> 3);
  const int m0 = (wg / 6) * 128, n0 = (wg % 6) * 128;
  const int tid = threadIdx.x;
  gemm_mainloop(Ab, WT, m0, n0, tid, As, Bs, acc);
  const int lane = tid & 63, wave = tid >> 6;
  const int wm = wave >> 1, wn = wave & 1, ln = lane & 15, quad = lane >> 4;
#pragma unroll
  for (int mi = 0; mi < 4; ++mi)
#pragma unroll
    for (int ni = 0; ni < 4; ++ni)
#pragma unroll
      for (int rg = 0; rg < 4; ++rg) {
        int m = m0 + wm * 64 + mi * 16 + quad * 4 + rg;
        int n = n0 + wn * 64 + ni * 16 + ln;
        Out[(size_t)m * 768 + n] = acc[mi][ni][rg] + bias[n];
      }
}

// ------- Flash attention R19: 2 waves x 32 rows, shared K/V frag reads -----
// Virtual tile space per (bh,qb) global row: vt 0..3 = g-tiles, vt>=4 ->
// causal kb=vt-4 (0..qb). T=qb+5 tiles split into ceil(T/8) parts of <=8.
// Grid 2560 x 128thr: [0,1536) global parts (slot==gid), [1536,2560) local.
// LDS rows are 64 u16 (128B) with 16B-slot XOR swizzle: slot ^= (row&7).
__global__ __launch_bounds__(128, 2) void attn_kernel(
    const unsigned short* __restrict__ QKV,   // [8192][2304]
    const unsigned short* __restrict__ Vtb,   // [48][64][2048]
    const unsigned short* __restrict__ Kg, const unsigned short* __restrict__ VgT,
    const int* __restrict__ gidx,
    unsigned short* __restrict__ AOut,        // [8192][768]
    unsigned short* __restrict__ Opart,       // [1536][4096] bf16
    float* __restrict__ Lpart) {              // [1536][64]
  __shared__ __attribute__((aligned(16))) unsigned short Ks[64 * 64];
  __shared__ __attribute__((aligned(16))) unsigned short Vs[64 * 64];
  __shared__ __attribute__((aligned(16))) unsigned short Ps[64 * 64];  // wave-private rows

  const int gid = blockIdx.x;
  int b, h, qb, vt0, vt1;
  bool multi = false;
  if (gid < 1536) {
    int bh = gid / 96, rem = gid % 96;
    b = bh >> 2; h = 8 + (bh & 3);
    int part;
    if (rem < 4)       { qb = rem;                               part = 0; }
    else if (rem < 20) { int z = rem - 4;  qb = 4 + (z >> 1);    part = z & 1; }
    else if (rem < 44) { int z = rem - 20; int q = z / 3; qb = 12 + q; part = z - 3 * q; }
    else if (rem < 76) { int z = rem - 44; qb = 20 + (z >> 2);   part = z & 3; }
    else               { int z = rem - 76; int q = z / 5; qb = 28 + q; part = z - 5 * q; }
    vt0 = part * 8;
    vt1 = min(vt0 + 8, qb + 5);
    multi = (qb >= 4);
  } else {
    int lid = gid - 1536;
    int bh = lid >> 5; b = bh >> 3; h = bh & 7; qb = lid & 31;
    vt0 = ((qb > 4) ? qb - 4 : 0) + 4;
    vt1 = qb + 5;
  }
  const int qb0 = qb * 64;
  const bool is_local = (h < 8);
  const int tid = threadIdx.x, lane = tid & 63, wave = tid >> 6;  // wave 0..1
  const int ln = lane & 15, quad = lane >> 4;
  const int bh48 = b * NH + h;
  const int bhg = (b << 2) | (h & 3);

  // Q fragments: 2 m-frags (16 rows each) per wave
  bf16x8 qA[2][2];
#pragma unroll
  for (int mf = 0; mf < 2; ++mf) {
    const size_t qoff = (size_t)(b * SQ + qb0 + wave * 32 + mf * 16 + ln) * 2304 + h * 64;
    qA[mf][0] = *(const bf16x8*)&QKV[qoff + quad * 8];
    qA[mf][1] = *(const bf16x8*)&QKV[qoff + 32 + quad * 8];
  }

  bf16x8 onesF;
#pragma unroll
  for (int z = 0; z < 8; ++z) onesF[z] = (__bf16)1.0f;

  f32x4 o[2][4];
  f32x4 ls[2];
#pragma unroll
  for (int mf = 0; mf < 2; ++mf) {
    ls[mf] = (f32x4){0.f, 0.f, 0.f, 0.f};
#pragma unroll
    for (int dt = 0; dt < 4; ++dt) o[mf][dt] = (f32x4){0.f, 0.f, 0.f, 0.f};
  }

  const int sr = tid >> 3, sch = tid & 7;           // staging row base / slot
  const int ssw = (sch ^ (sr & 7)) * 8;             // swizzled write slot (16*i keeps &7)
  const int s0k = (quad ^ (ln & 7)) * 8;            // frag read slot, cols 0..31
  const int s1k = ((quad + 4) ^ (ln & 7)) * 8;      // frag read slot, cols 32..63
  const int lnh = ln >> 3, ln7 = ln & 7;

  // exp2-folded softmax constants: p = exp2(c*S2 - B2) == exp(c/8 - 8)
  const float S2 = 0.125f * 1.44269504f, B2 = 8.0f * 1.44269504f;

  // T14 prefetch registers: next tile's K/V (32 VGPRs), static indexing
  uint4 pk[4], pv[4];
  auto issue_load = [&](int vt) {
    if (vt >= 4) {
      const int kstart = (vt - 4) * 64;
#pragma unroll
      for (int i = 0; i < 4; ++i) {
        pk[i] = *(const uint4*)&QKV[(size_t)(b * SQ + kstart + sr + 16 * i) * 2304 + 768 + h * 64 + sch * 8];
        pv[i] = *(const uint4*)&Vtb[(size_t)bh48 * 131072 + (size_t)(sr + 16 * i) * 2048 + kstart + sch * 8];
      }
    } else {
      const int kg0 = vt * 64;
#pragma unroll
      for (int i = 0; i < 4; ++i) {
        pk[i] = *(const uint4*)&Kg[((size_t)bhg * 256 + kg0 + sr + 16 * i) * 64 + sch * 8];
        pv[i] = *(const uint4*)&VgT[((size_t)bhg * 64 + sr + 16 * i) * 256 + kg0 + sch * 8];
      }
    }
  };
  issue_load(vt0);

  for (int vt = vt0; vt < vt1; ++vt) {
    const bool gph = (vt < 4);
    __syncthreads();  // barrier A: all waves done reading prev Ks/Vs
#pragma unroll
    for (int i = 0; i < 4; ++i) {
      *(uint4*)&Ks[(sr + 16 * i) * 64 + ssw] = pk[i];
      *(uint4*)&Vs[(sr + 16 * i) * 64 + ssw] = pv[i];
    }
    __syncthreads();  // barrier B: staged tile visible
    if (vt + 1 < vt1) issue_load(vt + 1);  // in flight across QK+SM+PV

    const int kstart = (vt - 4) * 64;  // valid when !gph
    const int kg0 = vt * 64;           // valid when gph
    bool fullm[2];
#pragma unroll
    for (int mf = 0; mf < 2; ++mf) {
      int iw = qb0 + wave * 32 + mf * 16;
      fullm[mf] = !gph && (kstart + 63 <= iw) && (!is_local || kstart >= iw - 241);
    }

    __bf16* P = (__bf16*)Ps;
#pragma unroll
    for (int nt = 0; nt < 4; ++nt) {
      // K fragments read ONCE, consumed by both m-frags
      bf16x8 kF0 = *(const bf16x8*)&Ks[(nt * 16 + ln) * 64 + s0k];
      bf16x8 kF1 = *(const bf16x8*)&Ks[(nt * 16 + ln) * 64 + s1k];
#pragma unroll
      for (int mf = 0; mf < 2; ++mf) {
        f32x4 c = (f32x4){0.f, 0.f, 0.f, 0.f};
        c = __builtin_amdgcn_mfma_f32_16x16x32_bf16(qA[mf][0], kF0, c, 0, 0, 0);
        c = __builtin_amdgcn_mfma_f32_16x16x32_bf16(qA[mf][1], kF1, c, 0, 0, 0);
        const int irow = qb0 + wave * 32 + mf * 16 + quad * 4;  // + rg
        float sc[4];
        if (fullm[mf]) {
#pragma unroll
          for (int rg = 0; rg < 4; ++rg) sc[rg] = c[rg] * S2 - B2;
        } else if (!gph) {
          int j = kstart + nt * 16 + ln;
#pragma unroll
          for (int rg = 0; rg < 4; ++rg) {
            int i = irow + rg;
            bool ok = is_local ? (j >= i - 256 && j <= i) : (j <= i);
            sc[rg] = ok ? (c[rg] * S2 - B2) : -1e9f;
          }
        } else {
          int jg = gidx[kg0 + nt * 16 + ln];
#pragma unroll
          for (int rg = 0; rg < 4; ++rg) {
            bool ok = jg > (irow + rg);
            sc[rg] = ok ? (c[rg] * S2 - B2) : -1e9f;
          }
        }
        // P write (wave-private rows; same-wave DS ordering -> no barrier)
#pragma unroll
        for (int rg = 0; rg < 4; ++rg) {
          int prow = wave * 32 + mf * 16 + quad * 4 + rg;
          P[prow * 64 + ln7 + (((nt * 2 + lnh) ^ (prow & 7)) << 3)] = (__bf16)exp2f(sc[rg]);
        }
      }
    }

    bf16x8 pF[2][2];
#pragma unroll
    for (int mf = 0; mf < 2; ++mf) {
      pF[mf][0] = *(const bf16x8*)&Ps[(wave * 32 + mf * 16 + ln) * 64 + s0k];
      pF[mf][1] = *(const bf16x8*)&Ps[(wave * 32 + mf * 16 + ln) * 64 + s1k];
      ls[mf] = __builtin_amdgcn_mfma_f32_16x16x32_bf16(pF[mf][0], onesF, ls[mf], 0, 0, 0);
      ls[mf] = __builtin_amdgcn_mfma_f32_16x16x32_bf16(pF[mf][1], onesF, ls[mf], 0, 0, 0);
    }
#pragma unroll
    for (int dt = 0; dt < 4; ++dt) {
      // V fragments read ONCE, consumed by both m-frags
      bf16x8 vF0 = *(const bf16x8*)&Vs[(dt * 16 + ln) * 64 + s0k];
      bf16x8 vF1 = *(const bf16x8*)&Vs[(dt * 16 + ln) * 64 + s1k];
#pragma unroll
      for (int mf = 0; mf < 2; ++mf) {
        o[mf][dt] = __builtin_amdgcn_mfma_f32_16x16x32_bf16(pF[mf][0], vF0, o[mf][dt], 0, 0, 0);
        o[mf][dt] = __builtin_amdgcn_mfma_f32_16x16x32_bf16(pF[mf][1], vF1, o[mf][dt], 0, 0, 0);
      }
    }
  }

  if (gid >= 1536 || !multi) {  // local + single-part global: direct write
#pragma unroll
    for (int mf = 0; mf < 2; ++mf)
#pragma unroll
      for (int dt = 0; dt < 4; ++dt)
#pragma unroll
        for (int rg = 0; rg < 4; ++rg) {
          int row = b * SQ + qb0 + wave * 32 + mf * 16 + quad * 4 + rg;
          int e = h * 64 + dt * 16 + ln;
          AOut[(size_t)row * 768 + e] = bfbits(o[mf][dt][rg] / ls[mf][rg]);
        }
  } else {  // multi-part global: partials (slot == gid)
#pragma unroll
    for (int mf = 0; mf < 2; ++mf)
#pragma unroll
      for (int dt = 0; dt < 4; ++dt)
#pragma unroll
        for (int rg = 0; rg < 4; ++rg) {
          int row = wave * 32 + mf * 16 + quad * 4 + rg;
          Opart[(size_t)gid * 4096 + row * 64 + dt * 16 + ln] = bfbits(o[mf][dt][rg]);
        }
    if (ln == 0) {
#pragma unroll
      for (int mf = 0; mf < 2; ++mf)
#pragma unroll
        for (int rg = 0; rg < 4; ++rg)
          Lpart[(size_t)gid * 64 + wave * 32 + mf * 16 + quad * 4 + rg] = ls[mf][rg];
    }
  }
}

// ---------------- combine split-K partials (global heads, qb>=4) -----------
__global__ __launch_bounds__(256) void combine_parts(
    const unsigned short* __restrict__ Opart, const float* __restrict__ Lpart,
    unsigned short* __restrict__ AOut) {
  const int bid = blockIdx.x;        // 448 = 16 bh * 28 (qb 4..31)
  const int bh = bid / 28, qb = bid % 28 + 4;
  const int b = bh >> 2, h = 8 + (bh & 3);
  int C, np;
  if (qb < 12)      { C = 2 * qb - 4;  np = 2; }
  else if (qb < 20) { C = 3 * qb - 16; np = 3; }
  else if (qb < 28) { C = 4 * qb - 36; np = 4; }
  else              { C = 5 * qb - 64; np = 5; }
  const int slot0 = bh * 96 + C;
  const int t = threadIdx.x, r = t >> 2, c0 = (t & 3) * 16;
  float acc[16];
#pragma unroll
  for (int z = 0; z < 16; ++z) acc[z] = 0.f;
  float l = 0.f;
  for (int p = 0; p < np; ++p) {
    const unsigned short* src = &Opart[(size_t)(slot0 + p) * 4096 + r * 64 + c0];
    bf16x8 v0 = *(const bf16x8*)&src[0];
    bf16x8 v1 = *(const bf16x8*)&src[8];
#pragma unroll
    for (int z = 0; z < 8; ++z) { acc[z] += (float)v0[z]; acc[8 + z] += (float)v1[z]; }
    l += Lpart[(size_t)(slot0 + p) * 64 + r];
  }
  float inv = 1.f / l;
  unsigned short pk[16];
#pragma unroll
  for (int z = 0; z < 16; ++z) pk[z] = bfbits(acc[z] * inv);
  size_t dst = (size_t)(b * SQ + qb * 64 + r) * 768 + h * 64 + c0;
  *(uint4*)&AOut[dst]     = *(uint4*)&pk[0];
  *(uint4*)&AOut[dst + 8] = *(uint4*)&pk[8];
}

// ---------------- launch ----------------
extern "C" void kernel_launch(void* const* d_in, const int* in_sizes, int n_in,
                              void* d_out, int out_size, void* d_ws, size_t ws_size,
                              hipStream_t stream) {
  const float* x      = (const float*)d_in[0];
  const float* w_attn = (const float*)d_in[1];
  const float* b_attn = (const float*)d_in[2];
  const float* w_proj = (const float*)d_in[3];
  const float* b_proj = (const float*)d_in[4];
  float* out = (float*)d_out;

  char* ws = (char*)d_ws;
  size_t off = 0;
  auto alloc = [&](size_t bytes) {
    void* p = ws + off;
    off += (bytes + 255) & ~(size_t)255;
    return p;
  };
  unsigned short* xb     = (unsigned short*)alloc((size_t)8192 * 768 * 2);   // reused as attn buf
  unsigned short* wattnT = (unsigned short*)alloc((size_t)2304 * 768 * 2);
  unsigned short* wprojT = (unsigned short*)alloc((size_t)768 * 768 * 2);
  unsigned short* qkvb   = (unsigned short*)alloc((size_t)8192 * 2304 * 2);
  unsigned short* Vtb    = (unsigned short*)alloc((size_t)48 * 64 * 2048 * 2);
  unsigned short* Kgb    = (unsigned short*)alloc((size_t)16 * 256 * 64 * 2);
  unsigned short* VgTb   = (unsigned short*)alloc((size_t)16 * 64 * 256 * 2);
  int* gidxb             = (int*)alloc((size_t)256 * 4);
  unsigned short* Opartb = (unsigned short*)alloc((size_t)1536 * 4096 * 2);
  float* Lpartb          = (float*)alloc((size_t)1536 * 64 * 4);
  unsigned short* attnb  = xb;  // xb dead after qkv_gemm

  prep<<<dim3(512 + 72 * 24 + 24 * 24), dim3(256), 0, stream>>>(
      x, xb, w_attn, wattnT, w_proj, wprojT);
  qkv_gemm<<<dim3(1152), dim3(256), 0, stream>>>(xb, wattnT, b_attn, qkvb, Vtb);
  vprep<<<dim3(128), dim3(256), 0, stream>>>(qkvb, Vtb, Kgb, VgTb, gidxb);
  attn_kernel<<<dim3(2560), dim3(128), 0, stream>>>(qkvb, Vtb, Kgb, VgTb, gidxb,
                                                    attnb, Opartb, Lpartb);
  combine_parts<<<dim3(448), dim3(256), 0, stream>>>(Opartb, Lpartb, attnb);
  proj_gemm<<<dim3(384), dim3(256), 0, stream>>>(attnb, wprojT, b_proj, out);
}

// Round 9
// 207.573 us; speedup vs baseline: 1.4674x; 1.4674x over previous
//
#include <hip/hip_runtime.h>
#include <stdint.h>

// SparseAttention MI355X bf16-MFMA pipeline. Output f32.
// R20: attn reverted to 4-wave (R18 structure; R19's 2-wave spilled: 92 regs
// alloc vs ~130 live -> 201MB scratch, 150us. Session rule: attn live state
// must stay <=~64 regs). Staging switched reg-prefetch -> global_load_lds
// DOUBLE-BUFFER (the R17/R18 GEMM schedule, verified correct):
//   stage(vt+1,buf^1) 4 insts -> vmcnt(4) (curr landed, next in flight;
//   never drain mid-loop) -> s_barrier -> compute -> lgkmcnt(0) -> s_barrier.
// Kills the 16 ds_write_b128/tile-unit reg->LDS phase AND frees 16 prefetch
// VGPRs. Swizzle kept both-sides with zero regs: gload_lds lane slot is
// linear (l&7 at row +l>>3), so pre-swizzling the GLOBAL source slot by
// (l&7)^(l>>3) gives LDS[r][s]=global slot s^(r&7) (read side unchanged).
// LDS 40KB (Ks[2]+Vs[2]+Ps) -> 4 blocks/CU, launch_bounds(256,4).
// R18 (kept): qkv V-panels write Vtb from acc; vprep gather-only; GEMM
// counted-vmcnt dbuf loop; XCD swizzles; exp2 fold.
// MFMA 16x16x32 bf16 layouts (HW-verified): A[m=lane&15][k=quad*8+j],
// B[k=quad*8+j][n=lane&15], C/D col=lane&15 row=quad*4+reg.

#define NH 12
#define SQ 2048

typedef __bf16 bf16x8 __attribute__((ext_vector_type(8)));
typedef float f32x4 __attribute__((ext_vector_type(4)));

#define GLOAD_LDS16(g, l)                                                      \
  __builtin_amdgcn_global_load_lds(                                            \
      (__attribute__((address_space(1))) void*)(g),                            \
      (__attribute__((address_space(3))) void*)(l), 16, 0, 0)

__device__ __forceinline__ unsigned short bfbits(float f) {
  __bf16 h = (__bf16)f;
  return *(unsigned short*)&h;
}

// ---------------- prep: x->bf16 + both weight transposes (1 kernel) --------
__global__ __launch_bounds__(256) void prep(
    const float* __restrict__ x, unsigned short* __restrict__ xb,
    const float* __restrict__ w_attn, unsigned short* __restrict__ wattnT,
    const float* __restrict__ w_proj, unsigned short* __restrict__ wprojT) {
  const int bid = blockIdx.x, t = threadIdx.x;
  if (bid < 512) {                 // convert x: 8192*768 floats
    const int n4 = 8192 * 768 / 4;
    for (int i = bid * 256 + t; i < n4; i += 512 * 256) {
      float4 v = ((const float4*)x)[i];
      ((ushort4*)xb)[i] = make_ushort4(bfbits(v.x), bfbits(v.y), bfbits(v.z), bfbits(v.w));
    }
    return;
  }
  __shared__ float tile[32][33];
  const float* in; unsigned short* out; int K, N, tl;
  if (bid < 512 + 72 * 24) { in = w_attn; out = wattnT; K = 768; N = 2304; tl = bid - 512; }
  else                     { in = w_proj; out = wprojT; K = 768; N = 768;  tl = bid - 512 - 72 * 24; }
  const int tpr = N / 32;
  const int n0 = (tl % tpr) * 32, k0 = (tl / tpr) * 32;
  const int tx = t & 31, ty = t >> 5;
  for (int r = ty; r < 32; r += 8) tile[r][tx] = in[(size_t)(k0 + r) * N + n0 + tx];
  __syncthreads();
  for (int r = ty; r < 32; r += 8) out[(size_t)(n0 + r) * K + k0 + tx] = bfbits(tile[tx][r]);
}

// ---------------- vprep: gcol gather only (V transpose in qkv) -------------
__global__ __launch_bounds__(256) void vprep(const unsigned short* __restrict__ QKV,
                                             const unsigned short* __restrict__ Vtb,
                                             unsigned short* __restrict__ Kg,
                                             unsigned short* __restrict__ VgT,
                                             int* __restrict__ gidx) {
  const int g = blockIdx.x, t = threadIdx.x;   // 128 = 16 bh * 8 chunks
  const int bh = g >> 3, y = g & 7;
  const int b = bh >> 2, h = 8 + (bh & 3);
  const int bh48 = b * NH + h;
  if (g == 0) {
    int c = t;
    gidx[c] = (c < 203) ? (int)((double)c * (2047.0 / 203.0)) : ((c == 203) ? 2047 : -1);
  }
  {  // Kg rows from qkvb K-section
    int c = t, ch = y;
    int col = (c < 203) ? (int)((double)c * (2047.0 / 203.0)) : ((c == 203) ? 2047 : -1);
    uint4 v = {0u, 0u, 0u, 0u};
    if (col >= 0) v = *(const uint4*)&QKV[(size_t)(b * SQ + col) * 2304 + 768 + h * 64 + ch * 8];
    *(uint4*)&Kg[((size_t)bh * 256 + c) * 64 + ch * 8] = v;
  }
  {  // VgT gathered from Vtb (written by qkv_gemm V-panels)
    int d = t >> 2;
    int cb = (t & 3) * 64 + y * 8;
    for (int cc = 0; cc < 8; ++cc) {
      int c = cb + cc;
      int col = (c < 203) ? (int)((double)c * (2047.0 / 203.0)) : ((c == 203) ? 2047 : -1);
      unsigned short v = 0;
      if (col >= 0) v = Vtb[(size_t)bh48 * 131072 + (size_t)d * 2048 + col];
      VgT[((size_t)bh * 64 + d) * 256 + c] = v;
    }
  }
}

// ---- GEMM mainloop: 128x128, BK=64, dbuf, counted vmcnt, raw barriers -----
__device__ __forceinline__ void gemm_mainloop(
    const unsigned short* __restrict__ A, const unsigned short* __restrict__ BT,
    int m0, int n0, int tid,
    unsigned short* As, unsigned short* Bs,    // each 2*128*64 u16
    f32x4 acc[4][4]) {
  const int lane = tid & 63, wave = tid >> 6;
  const int wm = wave >> 1, wn = wave & 1;
  const int ln = lane & 15, quad = lane >> 4, ln7 = lane & 7;
  const int srow = tid >> 3;                        // 0..31 (+rr*32)
  const int scol = ((tid & 7) ^ (srow & 7)) * 8;    // pre-swizzled source slot
  const int sbase = wave * 512;                     // u16; lane adds lane*8

#pragma unroll
  for (int mi = 0; mi < 4; ++mi)
#pragma unroll
    for (int ni = 0; ni < 4; ++ni) acc[mi][ni] = (f32x4){0.f, 0.f, 0.f, 0.f};

  auto stage = [&](int kt, int buf) {
    const int k0 = kt * 64;
    const int bo = buf * 8192;
#pragma unroll
    for (int rr = 0; rr < 4; ++rr) {
      GLOAD_LDS16(A  + (size_t)(m0 + rr * 32 + srow) * 768 + k0 + scol,
                  &As[bo + rr * 2048 + sbase]);
      GLOAD_LDS16(BT + (size_t)(n0 + rr * 32 + srow) * 768 + k0 + scol,
                  &Bs[bo + rr * 2048 + sbase]);
    }
  };

  stage(0, 0);
  int buf = 0;
  for (int kt = 0; kt < 12; ++kt) {
    if (kt < 11) {
      stage(kt + 1, buf ^ 1);   // next tile's 8 loads issued first
      asm volatile("s_waitcnt vmcnt(8)" ::: "memory");  // tile-t landed; 8 in flight
    } else {
      asm volatile("s_waitcnt vmcnt(0)" ::: "memory");  // last tile: drain
    }
    __builtin_amdgcn_sched_barrier(0);
    __builtin_amdgcn_s_barrier();                     // publish staged tile
    const int bo = buf * 8192;
#pragma unroll
    for (int kh = 0; kh < 2; ++kh) {
      const int sk = ((kh * 4 + quad) ^ ln7) * 8;
      bf16x8 aF[4], bF[4];
#pragma unroll
      for (int mi = 0; mi < 4; ++mi)
        aF[mi] = *(const bf16x8*)&As[bo + (wm * 64 + mi * 16 + ln) * 64 + sk];
#pragma unroll
      for (int ni = 0; ni < 4; ++ni)
        bF[ni] = *(const bf16x8*)&Bs[bo + (wn * 64 + ni * 16 + ln) * 64 + sk];
#pragma unroll
      for (int mi = 0; mi < 4; ++mi)
#pragma unroll
        for (int ni = 0; ni < 4; ++ni)
          acc[mi][ni] = __builtin_amdgcn_mfma_f32_16x16x32_bf16(aF[mi], bF[ni], acc[mi][ni], 0, 0, 0);
    }
    asm volatile("s_waitcnt lgkmcnt(0)" ::: "memory"); // all LDS reads done
    __builtin_amdgcn_sched_barrier(0);
    __builtin_amdgcn_s_barrier();                      // safe to overwrite buf
    buf ^= 1;
  }
}

// ---------------- QKV GEMM: Q/K -> qkvb row-major; V -> Vtb transposed -----
__global__ __launch_bounds__(256, 2) void qkv_gemm(
    const unsigned short* __restrict__ Xb, const unsigned short* __restrict__ WT,
    const float* __restrict__ bias, unsigned short* __restrict__ Out,
    unsigned short* __restrict__ Vtb) {
  __shared__ __attribute__((aligned(16))) unsigned short As[2 * 128 * 64];
  __shared__ __attribute__((aligned(16))) unsigned short Bs[2 * 128 * 64];
  f32x4 acc[4][4];
  // 1152 blocks (64 m x 18 n), 1152%8==0: chunked bijective XCD swizzle.
  const int wg = (blockIdx.x & 7) * 144 + (blockIdx.x >> 3);
  const int m0 = (wg / 18) * 128, n0 = (wg % 18) * 128;
  const int tid = threadIdx.x;
  gemm_mainloop(Xb, WT, m0, n0, tid, As, Bs, acc);
  const int lane = tid & 63, wave = tid >> 6;
  const int wm = wave >> 1, wn = wave & 1, ln = lane & 15, quad = lane >> 4;
  if (n0 < 1536) {   // Q/K panels: row-major bf16 qkvb
#pragma unroll
    for (int mi = 0; mi < 4; ++mi)
#pragma unroll
      for (int ni = 0; ni < 4; ++ni) {
        int n = n0 + wn * 64 + ni * 16 + ln;
        float bs = bias[n];
#pragma unroll
        for (int rg = 0; rg < 4; ++rg) {
          int m = m0 + wm * 64 + mi * 16 + quad * 4 + rg;
          Out[(size_t)m * 2304 + n] = bfbits(acc[mi][ni][rg] + bs);
        }
      }
  } else {           // V panels: write Vtb[bh48][d][key] directly from acc
    const int bb = m0 >> 11;                 // batch (128 | 2048)
    const int key0 = (m0 & 2047) + wm * 64;  // + mi*16 + quad*4 + rg
#pragma unroll
    for (int ni = 0; ni < 4; ++ni) {
      int e = (n0 - 1536) + wn * 64 + ni * 16 + ln;   // 0..767
      int h = e >> 6, d = e & 63;
      float bs = bias[1536 + e];
      size_t rowb = (size_t)(bb * NH + h) * 131072 + (size_t)d * 2048;
#pragma unroll
      for (int mi = 0; mi < 4; ++mi) {
        int key = key0 + mi * 16 + quad * 4;
        unsigned int w0 = (unsigned int)bfbits(acc[mi][ni][0] + bs) |
                          ((unsigned int)bfbits(acc[mi][ni][1] + bs) << 16);
        unsigned int w1 = (unsigned int)bfbits(acc[mi][ni][2] + bs) |
                          ((unsigned int)bfbits(acc[mi][ni][3] + bs) << 16);
        *(unsigned int*)&Vtb[rowb + key]     = w0;   // keys key..key+1
        *(unsigned int*)&Vtb[rowb + key + 2] = w1;   // keys key+2..key+3
      }
    }
  }
}

// ---------------- Proj GEMM: fp32 out (XCD-swizzled 1D grid) ---------------
__global__ __launch_bounds__(256, 2) void proj_gemm(
    const unsigned short* __restrict__ Ab, const unsigned short* __restrict__ WT,
    const float* __restrict__ bias, float* __restrict__ Out) {
  __shared__ __attribute__((aligned(16))) unsigned short As[2 * 128 * 64];
  __shared__ __attribute__((aligned(16))) unsigned short Bs[2 * 128 * 64];
  f32x4 acc[4][4];
  // 384 blocks (64 m x 6 n), 384%8==0.
  const int wg = (blockIdx.x & 7) * 48 + (blockIdx.x >> 3);
  const int m0 = (wg / 6) * 128, n0 = (wg % 6) * 128;
  const int tid = threadIdx.x;
  gemm_mainloop(Ab, WT, m0, n0, tid, As, Bs, acc);
  const int lane = tid & 63, wave = tid >> 6;
  const int wm = wave >> 1, wn = wave & 1, ln = lane & 15, quad = lane >> 4;
#pragma unroll
  for (int mi = 0; mi < 4; ++mi)
#pragma unroll
    for (int ni = 0; ni < 4; ++ni)
#pragma unroll
      for (int rg = 0; rg < 4; ++rg) {
        int m = m0 + wm * 64 + mi * 16 + quad * 4 + rg;
        int n = n0 + wn * 64 + ni * 16 + ln;
        Out[(size_t)m * 768 + n] = acc[mi][ni][rg] + bias[n];
      }
}

// --- Flash attention R20: 4-wave, gload_lds double-buffered K/V staging ----
// Virtual tile space per (bh,qb) global row: vt 0..3 = g-tiles, vt>=4 ->
// causal kb=vt-4 (0..qb). T=qb+5 tiles split into ceil(T/8) parts of <=8.
// Grid 2560 x 256thr: [0,1536) global parts (slot==gid), [1536,2560) local.
// LDS rows 64 u16 (128B), 16B-slot XOR swizzle LDS[r][s]=global slot
// s^(r&7), realized by linear gload_lds dest + pre-swizzled global source.
__global__ __launch_bounds__(256, 4) void attn_kernel(
    const unsigned short* __restrict__ QKV,   // [8192][2304]
    const unsigned short* __restrict__ Vtb,   // [48][64][2048]
    const unsigned short* __restrict__ Kg, const unsigned short* __restrict__ VgT,
    const int* __restrict__ gidx,
    unsigned short* __restrict__ AOut,        // [8192][768]
    unsigned short* __restrict__ Opart,       // [1536][4096] bf16
    float* __restrict__ Lpart) {              // [1536][64]
  __shared__ __attribute__((aligned(16))) unsigned short Ks[2][64 * 64];
  __shared__ __attribute__((aligned(16))) unsigned short Vs[2][64 * 64];
  __shared__ __attribute__((aligned(16))) unsigned short Ps[64 * 64];  // wave-private rows

  const int gid = blockIdx.x;
  int b, h, qb, vt0, vt1;
  bool multi = false;
  if (gid < 1536) {
    int bh = gid / 96, rem = gid % 96;
    b = bh >> 2; h = 8 + (bh & 3);
    int part;
    if (rem < 4)       { qb = rem;                               part = 0; }
    else if (rem < 20) { int z = rem - 4;  qb = 4 + (z >> 1);    part = z & 1; }
    else if (rem < 44) { int z = rem - 20; int q = z / 3; qb = 12 + q; part = z - 3 * q; }
    else if (rem < 76) { int z = rem - 44; qb = 20 + (z >> 2);   part = z & 3; }
    else               { int z = rem - 76; int q = z / 5; qb = 28 + q; part = z - 5 * q; }
    vt0 = part * 8;
    vt1 = min(vt0 + 8, qb + 5);
    multi = (qb >= 4);
  } else {
    int lid = gid - 1536;
    int bh = lid >> 5; b = bh >> 3; h = bh & 7; qb = lid & 31;
    vt0 = ((qb > 4) ? qb - 4 : 0) + 4;
    vt1 = qb + 5;
  }
  const int qb0 = qb * 64;
  const bool is_local = (h < 8);
  const int tid = threadIdx.x, lane = tid & 63, wave = tid >> 6;
  const int ln = lane & 15, quad = lane >> 4;
  const int bh48 = b * NH + h;
  const int bhg = (b << 2) | (h & 3);

  const size_t qoff = (size_t)(b * SQ + qb0 + wave * 16 + ln) * 2304 + h * 64;
  bf16x8 qA0 = *(const bf16x8*)&QKV[qoff + quad * 8];
  bf16x8 qA1 = *(const bf16x8*)&QKV[qoff + 32 + quad * 8];

  bf16x8 onesF;
#pragma unroll
  for (int z = 0; z < 8; ++z) onesF[z] = (__bf16)1.0f;

  f32x4 o[4];
  f32x4 ls = (f32x4){0.f, 0.f, 0.f, 0.f};
#pragma unroll
  for (int dt = 0; dt < 4; ++dt) o[dt] = (f32x4){0.f, 0.f, 0.f, 0.f};

  const int irow = qb0 + wave * 16 + quad * 4;  // + rg
  const int iw = qb0 + wave * 16;
  // read-side swizzled slots (u16 units)
  const int s0k = (quad ^ (ln & 7)) * 8;            // frag read slot, cols 0..31
  const int s1k = ((quad + 4) ^ (ln & 7)) * 8;      // frag read slot, cols 32..63
  const int lnh = ln >> 3, ln7 = ln & 7;
  // gload_lds staging: per wave, inst p covers rows r0..r0+7 (r0=(wave*2+p)*8),
  // lane l -> row r0+(l>>3), linear slot l&7; source slot pre-swizzled:
  const int srw = lane >> 3;                        // row-within-group 0..7
  const int scol = ((lane & 7) ^ srw) * 8;          // global elem offset

  // exp2-folded softmax constants: p = exp2(c*S2 - B2) == exp(c/8 - 8)
  const float S2 = 0.125f * 1.44269504f, B2 = 8.0f * 1.44269504f;

  auto stage = [&](int vt, int bufsel) {
#pragma unroll
    for (int p = 0; p < 2; ++p) {
      const int r0 = (wave * 2 + p) * 8;
      const int ldso = (wave * 2 + p) * 512;   // u16 offset of 1KB chunk
      if (vt >= 4) {
        const int kstart = (vt - 4) * 64;
        GLOAD_LDS16(QKV + (size_t)(b * SQ + kstart + r0 + srw) * 2304 + 768 + h * 64 + scol,
                    &Ks[bufsel][ldso]);
        GLOAD_LDS16(Vtb + (size_t)bh48 * 131072 + (size_t)(r0 + srw) * 2048 + kstart + scol,
                    &Vs[bufsel][ldso]);
      } else {
        const int kg0 = vt * 64;
        GLOAD_LDS16(Kg  + ((size_t)bhg * 256 + kg0 + r0 + srw) * 64 + scol,
                    &Ks[bufsel][ldso]);
        GLOAD_LDS16(VgT + ((size_t)bhg * 64 + r0 + srw) * 256 + kg0 + scol,
                    &Vs[bufsel][ldso]);
      }
    }
  };

  stage(vt0, 0);
  int buf = 0;
  for (int vt = vt0; vt < vt1; ++vt) {
    const bool gph = (vt < 4);
    if (vt + 1 < vt1) {
      stage(vt + 1, buf ^ 1);   // 4 loads issued before waiting on current
      asm volatile("s_waitcnt vmcnt(4)" ::: "memory");  // curr landed; 4 in flight
    } else {
      asm volatile("s_waitcnt vmcnt(0)" ::: "memory");
    }
    __builtin_amdgcn_sched_barrier(0);
    __builtin_amdgcn_s_barrier();   // staged tile visible to all waves

    const int kstart = (vt - 4) * 64;  // valid when !gph
    const int kg0 = vt * 64;           // valid when gph
    float sc[4][4];
    const bool full = !gph && (kstart + 63 <= iw) && (!is_local || kstart >= iw - 241);
#pragma unroll
    for (int nt = 0; nt < 4; ++nt) {
      bf16x8 kF0 = *(const bf16x8*)&Ks[buf][(nt * 16 + ln) * 64 + s0k];
      bf16x8 kF1 = *(const bf16x8*)&Ks[buf][(nt * 16 + ln) * 64 + s1k];
      f32x4 c = (f32x4){0.f, 0.f, 0.f, 0.f};
      c = __builtin_amdgcn_mfma_f32_16x16x32_bf16(qA0, kF0, c, 0, 0, 0);
      c = __builtin_amdgcn_mfma_f32_16x16x32_bf16(qA1, kF1, c, 0, 0, 0);
      if (full) {
#pragma unroll
        for (int rg = 0; rg < 4; ++rg) sc[nt][rg] = c[rg] * S2 - B2;
      } else if (!gph) {
        int j = kstart + nt * 16 + ln;
#pragma unroll
        for (int rg = 0; rg < 4; ++rg) {
          int i = irow + rg;
          bool ok = is_local ? (j >= i - 256 && j <= i) : (j <= i);
          sc[nt][rg] = ok ? (c[rg] * S2 - B2) : -1e9f;
        }
      } else {
        int jg = gidx[kg0 + nt * 16 + ln];
#pragma unroll
        for (int rg = 0; rg < 4; ++rg) {
          bool ok = jg > (irow + rg);
          sc[nt][rg] = ok ? (c[rg] * S2 - B2) : -1e9f;
        }
      }
    }

    // P in its own buffer: each wave writes+reads only rows wave*16..+15 ->
    // no barrier (same-wave DS ordering).
    __bf16* P = (__bf16*)Ps;
#pragma unroll
    for (int rg = 0; rg < 4; ++rg) {
      int prow = wave * 16 + quad * 4 + rg;
      int pbase = prow * 64 + ln7;
      int pr7 = prow & 7;
#pragma unroll
      for (int nt = 0; nt < 4; ++nt)
        P[pbase + (((nt * 2 + lnh) ^ pr7) << 3)] = (__bf16)exp2f(sc[nt][rg]);
    }
    bf16x8 pF0 = *(const bf16x8*)&Ps[(wave * 16 + ln) * 64 + s0k];
    bf16x8 pF1 = *(const bf16x8*)&Ps[(wave * 16 + ln) * 64 + s1k];
    ls = __builtin_amdgcn_mfma_f32_16x16x32_bf16(pF0, onesF, ls, 0, 0, 0);
    ls = __builtin_amdgcn_mfma_f32_16x16x32_bf16(pF1, onesF, ls, 0, 0, 0);
#pragma unroll
    for (int dt = 0; dt < 4; ++dt) {
      bf16x8 vF0 = *(const bf16x8*)&Vs[buf][(dt * 16 + ln) * 64 + s0k];
      bf16x8 vF1 = *(const bf16x8*)&Vs[buf][(dt * 16 + ln) * 64 + s1k];
      o[dt] = __builtin_amdgcn_mfma_f32_16x16x32_bf16(pF0, vF0, o[dt], 0, 0, 0);
      o[dt] = __builtin_amdgcn_mfma_f32_16x16x32_bf16(pF1, vF1, o[dt], 0, 0, 0);
    }

    asm volatile("s_waitcnt lgkmcnt(0)" ::: "memory"); // buf reads done
    __builtin_amdgcn_sched_barrier(0);
    __builtin_amdgcn_s_barrier();                      // safe to overwrite buf
    buf ^= 1;
  }

  if (gid >= 1536 || !multi) {  // local + single-part global: direct write
#pragma unroll
    for (int dt = 0; dt < 4; ++dt)
#pragma unroll
      for (int rg = 0; rg < 4; ++rg) {
        int row = b * SQ + qb0 + wave * 16 + quad * 4 + rg;
        int e = h * 64 + dt * 16 + ln;
        AOut[(size_t)row * 768 + e] = bfbits(o[dt][rg] / ls[rg]);
      }
  } else {  // multi-part global: partials (slot == gid)
#pragma unroll
    for (int dt = 0; dt < 4; ++dt)
#pragma unroll
      for (int rg = 0; rg < 4; ++rg) {
        int row = wave * 16 + quad * 4 + rg;
        Opart[(size_t)gid * 4096 + row * 64 + dt * 16 + ln] = bfbits(o[dt][rg]);
      }
    if (ln == 0) {
#pragma unroll
      for (int rg = 0; rg < 4; ++rg)
        Lpart[(size_t)gid * 64 + wave * 16 + quad * 4 + rg] = ls[rg];
    }
  }
}

// ---------------- combine split-K partials (global heads, qb>=4) -----------
__global__ __launch_bounds__(256) void combine_parts(
    const unsigned short* __restrict__ Opart, const float* __restrict__ Lpart,
    unsigned short* __restrict__ AOut) {
  const int bid = blockIdx.x;        // 448 = 16 bh * 28 (qb 4..31)
  const int bh = bid / 28, qb = bid % 28 + 4;
  const int b = bh >> 2, h = 8 + (bh & 3);
  int C, np;
  if (qb < 12)      { C = 2 * qb - 4;  np = 2; }
  else if (qb < 20) { C = 3 * qb - 16; np = 3; }
  else if (qb < 28) { C = 4 * qb - 36; np = 4; }
  else              { C = 5 * qb - 64; np = 5; }
  const int slot0 = bh * 96 + C;
  const int t = threadIdx.x, r = t >> 2, c0 = (t & 3) * 16;
  float acc[16];
#pragma unroll
  for (int z = 0; z < 16; ++z) acc[z] = 0.f;
  float l = 0.f;
  for (int p = 0; p < np; ++p) {
    const unsigned short* src = &Opart[(size_t)(slot0 + p) * 4096 + r * 64 + c0];
    bf16x8 v0 = *(const bf16x8*)&src[0];
    bf16x8 v1 = *(const bf16x8*)&src[8];
#pragma unroll
    for (int z = 0; z < 8; ++z) { acc[z] += (float)v0[z]; acc[8 + z] += (float)v1[z]; }
    l += Lpart[(size_t)(slot0 + p) * 64 + r];
  }
  float inv = 1.f / l;
  unsigned short pk[16];
#pragma unroll
  for (int z = 0; z < 16; ++z) pk[z] = bfbits(acc[z] * inv);
  size_t dst = (size_t)(b * SQ + qb * 64 + r) * 768 + h * 64 + c0;
  *(uint4*)&AOut[dst]     = *(uint4*)&pk[0];
  *(uint4*)&AOut[dst + 8] = *(uint4*)&pk[8];
}

// ---------------- launch ----------------
extern "C" void kernel_launch(void* const* d_in, const int* in_sizes, int n_in,
                              void* d_out, int out_size, void* d_ws, size_t ws_size,
                              hipStream_t stream) {
  const float* x      = (const float*)d_in[0];
  const float* w_attn = (const float*)d_in[1];
  const float* b_attn = (const float*)d_in[2];
  const float* w_proj = (const float*)d_in[3];
  const float* b_proj = (const float*)d_in[4];
  float* out = (float*)d_out;

  char* ws = (char*)d_ws;
  size_t off = 0;
  auto alloc = [&](size_t bytes) {
    void* p = ws + off;
    off += (bytes + 255) & ~(size_t)255;
    return p;
  };
  unsigned short* xb     = (unsigned short*)alloc((size_t)8192 * 768 * 2);   // reused as attn buf
  unsigned short* wattnT = (unsigned short*)alloc((size_t)2304 * 768 * 2);
  unsigned short* wprojT = (unsigned short*)alloc((size_t)768 * 768 * 2);
  unsigned short* qkvb   = (unsigned short*)alloc((size_t)8192 * 2304 * 2);
  unsigned short* Vtb    = (unsigned short*)alloc((size_t)48 * 64 * 2048 * 2);
  unsigned short* Kgb    = (unsigned short*)alloc((size_t)16 * 256 * 64 * 2);
  unsigned short* VgTb   = (unsigned short*)alloc((size_t)16 * 64 * 256 * 2);
  int* gidxb             = (int*)alloc((size_t)256 * 4);
  unsigned short* Opartb = (unsigned short*)alloc((size_t)1536 * 4096 * 2);
  float* Lpartb          = (float*)alloc((size_t)1536 * 64 * 4);
  unsigned short* attnb  = xb;  // xb dead after qkv_gemm

  prep<<<dim3(512 + 72 * 24 + 24 * 24), dim3(256), 0, stream>>>(
      x, xb, w_attn, wattnT, w_proj, wprojT);
  qkv_gemm<<<dim3(1152), dim3(256), 0, stream>>>(xb, wattnT, b_attn, qkvb, Vtb);
  vprep<<<dim3(128), dim3(256), 0, stream>>>(qkvb, Vtb, Kgb, VgTb, gidxb);
  attn_kernel<<<dim3(2560), dim3(256), 0, stream>>>(qkvb, Vtb, Kgb, VgTb, gidxb,
                                                    attnb, Opartb, Lpartb);
  combine_parts<<<dim3(448), dim3(256), 0, stream>>>(Opartb, Lpartb, attnb);
  proj_gemm<<<dim3(384), dim3(256), 0, stream>>>(attnb, wprojT, b_proj, out);
}

// Round 11
// 207.347 us; speedup vs baseline: 1.4690x; 1.0011x over previous
//
#include <hip/hip_runtime.h>
#include <stdint.h>

// SparseAttention MI355X bf16-MFMA pipeline. Output f32.
// R22: R10's fused split-K combine REVERTED (cross-XCD release protocol
// leaked: only-tid0 fence after syncthreads doesn't release other waves'
// stores -> absmax 1.57; G16 hazard, not worth remote-debugging). Back to
// separate combine_parts (R9 known-good, 207.6us). Salvage lever: T5
// s_setprio(1) around attn's two MFMA clusters only (QK nt-loop, PV
// dt-loop; exp/P-write stays prio 0). Regime check: attn has 4 independent
// blocks/CU at staggered phases = m191's +4-7% regime, NOT m190's lockstep
// null regime.
// R20 (kept): attn 4-wave gload_lds dbuf counted-vmcnt staging (52us, VGPR
// 60, no spill, conflicts 0). R18: qkv V-panels write Vtb from acc; vprep
// gather-only; GEMM counted-vmcnt dbuf loop; XCD swizzles; exp2 fold.
// MFMA 16x16x32 bf16 layouts (HW-verified): A[m=lane&15][k=quad*8+j],
// B[k=quad*8+j][n=lane&15], C/D col=lane&15 row=quad*4+reg.

#define NH 12
#define SQ 2048

typedef __bf16 bf16x8 __attribute__((ext_vector_type(8)));
typedef float f32x4 __attribute__((ext_vector_type(4)));

#define GLOAD_LDS16(g, l)                                                      \
  __builtin_amdgcn_global_load_lds(                                            \
      (__attribute__((address_space(1))) void*)(g),                            \
      (__attribute__((address_space(3))) void*)(l), 16, 0, 0)

__device__ __forceinline__ unsigned short bfbits(float f) {
  __bf16 h = (__bf16)f;
  return *(unsigned short*)&h;
}

// ---------------- prep: x->bf16 + both weight transposes (1 kernel) --------
__global__ __launch_bounds__(256) void prep(
    const float* __restrict__ x, unsigned short* __restrict__ xb,
    const float* __restrict__ w_attn, unsigned short* __restrict__ wattnT,
    const float* __restrict__ w_proj, unsigned short* __restrict__ wprojT) {
  const int bid = blockIdx.x, t = threadIdx.x;
  if (bid < 512) {                 // convert x: 8192*768 floats
    const int n4 = 8192 * 768 / 4;
    for (int i = bid * 256 + t; i < n4; i += 512 * 256) {
      float4 v = ((const float4*)x)[i];
      ((ushort4*)xb)[i] = make_ushort4(bfbits(v.x), bfbits(v.y), bfbits(v.z), bfbits(v.w));
    }
    return;
  }
  __shared__ float tile[32][33];
  const float* in; unsigned short* out; int K, N, tl;
  if (bid < 512 + 72 * 24) { in = w_attn; out = wattnT; K = 768; N = 2304; tl = bid - 512; }
  else                     { in = w_proj; out = wprojT; K = 768; N = 768;  tl = bid - 512 - 72 * 24; }
  const int tpr = N / 32;
  const int n0 = (tl % tpr) * 32, k0 = (tl / tpr) * 32;
  const int tx = t & 31, ty = t >> 5;
  for (int r = ty; r < 32; r += 8) tile[r][tx] = in[(size_t)(k0 + r) * N + n0 + tx];
  __syncthreads();
  for (int r = ty; r < 32; r += 8) out[(size_t)(n0 + r) * K + k0 + tx] = bfbits(tile[tx][r]);
}

// ---------------- vprep: gcol gather only (V transpose in qkv) -------------
__global__ __launch_bounds__(256) void vprep(const unsigned short* __restrict__ QKV,
                                             const unsigned short* __restrict__ Vtb,
                                             unsigned short* __restrict__ Kg,
                                             unsigned short* __restrict__ VgT,
                                             int* __restrict__ gidx) {
  const int g = blockIdx.x, t = threadIdx.x;   // 128 = 16 bh * 8 chunks
  const int bh = g >> 3, y = g & 7;
  const int b = bh >> 2, h = 8 + (bh & 3);
  const int bh48 = b * NH + h;
  if (g == 0) {
    int c = t;
    gidx[c] = (c < 203) ? (int)((double)c * (2047.0 / 203.0)) : ((c == 203) ? 2047 : -1);
  }
  {  // Kg rows from qkvb K-section
    int c = t, ch = y;
    int col = (c < 203) ? (int)((double)c * (2047.0 / 203.0)) : ((c == 203) ? 2047 : -1);
    uint4 v = {0u, 0u, 0u, 0u};
    if (col >= 0) v = *(const uint4*)&QKV[(size_t)(b * SQ + col) * 2304 + 768 + h * 64 + ch * 8];
    *(uint4*)&Kg[((size_t)bh * 256 + c) * 64 + ch * 8] = v;
  }
  {  // VgT gathered from Vtb (written by qkv_gemm V-panels)
    int d = t >> 2;
    int cb = (t & 3) * 64 + y * 8;
    for (int cc = 0; cc < 8; ++cc) {
      int c = cb + cc;
      int col = (c < 203) ? (int)((double)c * (2047.0 / 203.0)) : ((c == 203) ? 2047 : -1);
      unsigned short v = 0;
      if (col >= 0) v = Vtb[(size_t)bh48 * 131072 + (size_t)d * 2048 + col];
      VgT[((size_t)bh * 64 + d) * 256 + c] = v;
    }
  }
}

// ---- GEMM mainloop: 128x128, BK=64, dbuf, counted vmcnt, raw barriers -----
__device__ __forceinline__ void gemm_mainloop(
    const unsigned short* __restrict__ A, const unsigned short* __restrict__ BT,
    int m0, int n0, int tid,
    unsigned short* As, unsigned short* Bs,    // each 2*128*64 u16
    f32x4 acc[4][4]) {
  const int lane = tid & 63, wave = tid >> 6;
  const int wm = wave >> 1, wn = wave & 1;
  const int ln = lane & 15, quad = lane >> 4, ln7 = lane & 7;
  const int srow = tid >> 3;                        // 0..31 (+rr*32)
  const int scol = ((tid & 7) ^ (srow & 7)) * 8;    // pre-swizzled source slot
  const int sbase = wave * 512;                     // u16; lane adds lane*8

#pragma unroll
  for (int mi = 0; mi < 4; ++mi)
#pragma unroll
    for (int ni = 0; ni < 4; ++ni) acc[mi][ni] = (f32x4){0.f, 0.f, 0.f, 0.f};

  auto stage = [&](int kt, int buf) {
    const int k0 = kt * 64;
    const int bo = buf * 8192;
#pragma unroll
    for (int rr = 0; rr < 4; ++rr) {
      GLOAD_LDS16(A  + (size_t)(m0 + rr * 32 + srow) * 768 + k0 + scol,
                  &As[bo + rr * 2048 + sbase]);
      GLOAD_LDS16(BT + (size_t)(n0 + rr * 32 + srow) * 768 + k0 + scol,
                  &Bs[bo + rr * 2048 + sbase]);
    }
  };

  stage(0, 0);
  int buf = 0;
  for (int kt = 0; kt < 12; ++kt) {
    if (kt < 11) {
      stage(kt + 1, buf ^ 1);   // next tile's 8 loads issued first
      asm volatile("s_waitcnt vmcnt(8)" ::: "memory");  // tile-t landed; 8 in flight
    } else {
      asm volatile("s_waitcnt vmcnt(0)" ::: "memory");  // last tile: drain
    }
    __builtin_amdgcn_sched_barrier(0);
    __builtin_amdgcn_s_barrier();                     // publish staged tile
    const int bo = buf * 8192;
#pragma unroll
    for (int kh = 0; kh < 2; ++kh) {
      const int sk = ((kh * 4 + quad) ^ ln7) * 8;
      bf16x8 aF[4], bF[4];
#pragma unroll
      for (int mi = 0; mi < 4; ++mi)
        aF[mi] = *(const bf16x8*)&As[bo + (wm * 64 + mi * 16 + ln) * 64 + sk];
#pragma unroll
      for (int ni = 0; ni < 4; ++ni)
        bF[ni] = *(const bf16x8*)&Bs[bo + (wn * 64 + ni * 16 + ln) * 64 + sk];
#pragma unroll
      for (int mi = 0; mi < 4; ++mi)
#pragma unroll
        for (int ni = 0; ni < 4; ++ni)
          acc[mi][ni] = __builtin_amdgcn_mfma_f32_16x16x32_bf16(aF[mi], bF[ni], acc[mi][ni], 0, 0, 0);
    }
    asm volatile("s_waitcnt lgkmcnt(0)" ::: "memory"); // all LDS reads done
    __builtin_amdgcn_sched_barrier(0);
    __builtin_amdgcn_s_barrier();                      // safe to overwrite buf
    buf ^= 1;
  }
}

// ---------------- QKV GEMM: Q/K -> qkvb row-major; V -> Vtb transposed -----
__global__ __launch_bounds__(256, 2) void qkv_gemm(
    const unsigned short* __restrict__ Xb, const unsigned short* __restrict__ WT,
    const float* __restrict__ bias, unsigned short* __restrict__ Out,
    unsigned short* __restrict__ Vtb) {
  __shared__ __attribute__((aligned(16))) unsigned short As[2 * 128 * 64];
  __shared__ __attribute__((aligned(16))) unsigned short Bs[2 * 128 * 64];
  f32x4 acc[4][4];
  // 1152 blocks (64 m x 18 n), 1152%8==0: chunked bijective XCD swizzle.
  const int wg = (blockIdx.x & 7) * 144 + (blockIdx.x >> 3);
  const int m0 = (wg / 18) * 128, n0 = (wg % 18) * 128;
  const int tid = threadIdx.x;
  gemm_mainloop(Xb, WT, m0, n0, tid, As, Bs, acc);
  const int lane = tid & 63, wave = tid >> 6;
  const int wm = wave >> 1, wn = wave & 1, ln = lane & 15, quad = lane >> 4;
  if (n0 < 1536) {   // Q/K panels: row-major bf16 qkvb
#pragma unroll
    for (int mi = 0; mi < 4; ++mi)
#pragma unroll
      for (int ni = 0; ni < 4; ++ni) {
        int n = n0 + wn * 64 + ni * 16 + ln;
        float bs = bias[n];
#pragma unroll
        for (int rg = 0; rg < 4; ++rg) {
          int m = m0 + wm * 64 + mi * 16 + quad * 4 + rg;
          Out[(size_t)m * 2304 + n] = bfbits(acc[mi][ni][rg] + bs);
        }
      }
  } else {           // V panels: write Vtb[bh48][d][key] directly from acc
    const int bb = m0 >> 11;                 // batch (128 | 2048)
    const int key0 = (m0 & 2047) + wm * 64;  // + mi*16 + quad*4 + rg
#pragma unroll
    for (int ni = 0; ni < 4; ++ni) {
      int e = (n0 - 1536) + wn * 64 + ni * 16 + ln;   // 0..767
      int h = e >> 6, d = e & 63;
      float bs = bias[1536 + e];
      size_t rowb = (size_t)(bb * NH + h) * 131072 + (size_t)d * 2048;
#pragma unroll
      for (int mi = 0; mi < 4; ++mi) {
        int key = key0 + mi * 16 + quad * 4;
        unsigned int w0 = (unsigned int)bfbits(acc[mi][ni][0] + bs) |
                          ((unsigned int)bfbits(acc[mi][ni][1] + bs) << 16);
        unsigned int w1 = (unsigned int)bfbits(acc[mi][ni][2] + bs) |
                          ((unsigned int)bfbits(acc[mi][ni][3] + bs) << 16);
        *(unsigned int*)&Vtb[rowb + key]     = w0;   // keys key..key+1
        *(unsigned int*)&Vtb[rowb + key + 2] = w1;   // keys key+2..key+3
      }
    }
  }
}

// ---------------- Proj GEMM: fp32 out (XCD-swizzled 1D grid) ---------------
__global__ __launch_bounds__(256, 2) void proj_gemm(
    const unsigned short* __restrict__ Ab, const unsigned short* __restrict__ WT,
    const float* __restrict__ bias, float* __restrict__ Out) {
  __shared__ __attribute__((aligned(16))) unsigned short As[2 * 128 * 64];
  __shared__ __attribute__((aligned(16))) unsigned short Bs[2 * 128 * 64];
  f32x4 acc[4][4];
  // 384 blocks (64 m x 6 n), 384%8==0.
  const int wg = (blockIdx.x & 7) * 48 + (blockIdx.x >> 3);
  const int m0 = (wg / 6) * 128, n0 = (wg % 6) * 128;
  const int tid = threadIdx.x;
  gemm_mainloop(Ab, WT, m0, n0, tid, As, Bs, acc);
  const int lane = tid & 63, wave = tid >> 6;
  const int wm = wave >> 1, wn = wave & 1, ln = lane & 15, quad = lane >> 4;
#pragma unroll
  for (int mi = 0; mi < 4; ++mi)
#pragma unroll
    for (int ni = 0; ni < 4; ++ni)
#pragma unroll
      for (int rg = 0; rg < 4; ++rg) {
        int m = m0 + wm * 64 + mi * 16 + quad * 4 + rg;
        int n = n0 + wn * 64 + ni * 16 + ln;
        Out[(size_t)m * 768 + n] = acc[mi][ni][rg] + bias[n];
      }
}

// --- Flash attention R22: R20 staging + T5 setprio on MFMA clusters --------
// Virtual tile space per (bh,qb) global row: vt 0..3 = g-tiles, vt>=4 ->
// causal kb=vt-4 (0..qb). T=qb+5 tiles split into ceil(T/8) parts of <=8.
// Grid 2560 x 256thr: [0,1536) global parts (slot==gid), [1536,2560) local.
// LDS rows 64 u16 (128B), 16B-slot XOR swizzle LDS[r][s]=global slot
// s^(r&7), realized by linear gload_lds dest + pre-swizzled global source.
__global__ __launch_bounds__(256, 4) void attn_kernel(
    const unsigned short* __restrict__ QKV,   // [8192][2304]
    const unsigned short* __restrict__ Vtb,   // [48][64][2048]
    const unsigned short* __restrict__ Kg, const unsigned short* __restrict__ VgT,
    const int* __restrict__ gidx,
    unsigned short* __restrict__ AOut,        // [8192][768]
    unsigned short* __restrict__ Opart,       // [1536][4096] bf16
    float* __restrict__ Lpart) {              // [1536][64]
  __shared__ __attribute__((aligned(16))) unsigned short Ks[2][64 * 64];
  __shared__ __attribute__((aligned(16))) unsigned short Vs[2][64 * 64];
  __shared__ __attribute__((aligned(16))) unsigned short Ps[64 * 64];  // wave-private rows

  const int gid = blockIdx.x;
  int b, h, qb, vt0, vt1;
  bool multi = false;
  if (gid < 1536) {
    int bh = gid / 96, rem = gid % 96;
    b = bh >> 2; h = 8 + (bh & 3);
    int part;
    if (rem < 4)       { qb = rem;                               part = 0; }
    else if (rem < 20) { int z = rem - 4;  qb = 4 + (z >> 1);    part = z & 1; }
    else if (rem < 44) { int z = rem - 20; int q = z / 3; qb = 12 + q; part = z - 3 * q; }
    else if (rem < 76) { int z = rem - 44; qb = 20 + (z >> 2);   part = z & 3; }
    else               { int z = rem - 76; int q = z / 5; qb = 28 + q; part = z - 5 * q; }
    vt0 = part * 8;
    vt1 = min(vt0 + 8, qb + 5);
    multi = (qb >= 4);
  } else {
    int lid = gid - 1536;
    int bh = lid >> 5; b = bh >> 3; h = bh & 7; qb = lid & 31;
    vt0 = ((qb > 4) ? qb - 4 : 0) + 4;
    vt1 = qb + 5;
  }
  const int qb0 = qb * 64;
  const bool is_local = (h < 8);
  const int tid = threadIdx.x, lane = tid & 63, wave = tid >> 6;
  const int ln = lane & 15, quad = lane >> 4;
  const int bh48 = b * NH + h;
  const int bhg = (b << 2) | (h & 3);

  const size_t qoff = (size_t)(b * SQ + qb0 + wave * 16 + ln) * 2304 + h * 64;
  bf16x8 qA0 = *(const bf16x8*)&QKV[qoff + quad * 8];
  bf16x8 qA1 = *(const bf16x8*)&QKV[qoff + 32 + quad * 8];

  bf16x8 onesF;
#pragma unroll
  for (int z = 0; z < 8; ++z) onesF[z] = (__bf16)1.0f;

  f32x4 o[4];
  f32x4 ls = (f32x4){0.f, 0.f, 0.f, 0.f};
#pragma unroll
  for (int dt = 0; dt < 4; ++dt) o[dt] = (f32x4){0.f, 0.f, 0.f, 0.f};

  const int irow = qb0 + wave * 16 + quad * 4;  // + rg
  const int iw = qb0 + wave * 16;
  // read-side swizzled slots (u16 units)
  const int s0k = (quad ^ (ln & 7)) * 8;            // frag read slot, cols 0..31
  const int s1k = ((quad + 4) ^ (ln & 7)) * 8;      // frag read slot, cols 32..63
  const int lnh = ln >> 3, ln7 = ln & 7;
  // gload_lds staging: per wave, inst p covers rows r0..r0+7 (r0=(wave*2+p)*8),
  // lane l -> row r0+(l>>3), linear slot l&7; source slot pre-swizzled:
  const int srw = lane >> 3;                        // row-within-group 0..7
  const int scol = ((lane & 7) ^ srw) * 8;          // global elem offset

  // exp2-folded softmax constants: p = exp2(c*S2 - B2) == exp(c/8 - 8)
  const float S2 = 0.125f * 1.44269504f, B2 = 8.0f * 1.44269504f;

  auto stage = [&](int vt, int bufsel) {
#pragma unroll
    for (int p = 0; p < 2; ++p) {
      const int r0 = (wave * 2 + p) * 8;
      const int ldso = (wave * 2 + p) * 512;   // u16 offset of 1KB chunk
      if (vt >= 4) {
        const int kstart = (vt - 4) * 64;
        GLOAD_LDS16(QKV + (size_t)(b * SQ + kstart + r0 + srw) * 2304 + 768 + h * 64 + scol,
                    &Ks[bufsel][ldso]);
        GLOAD_LDS16(Vtb + (size_t)bh48 * 131072 + (size_t)(r0 + srw) * 2048 + kstart + scol,
                    &Vs[bufsel][ldso]);
      } else {
        const int kg0 = vt * 64;
        GLOAD_LDS16(Kg  + ((size_t)bhg * 256 + kg0 + r0 + srw) * 64 + scol,
                    &Ks[bufsel][ldso]);
        GLOAD_LDS16(VgT + ((size_t)bhg * 64 + r0 + srw) * 256 + kg0 + scol,
                    &Vs[bufsel][ldso]);
      }
    }
  };

  stage(vt0, 0);
  int buf = 0;
  for (int vt = vt0; vt < vt1; ++vt) {
    const bool gph = (vt < 4);
    if (vt + 1 < vt1) {
      stage(vt + 1, buf ^ 1);   // 4 loads issued before waiting on current
      asm volatile("s_waitcnt vmcnt(4)" ::: "memory");  // curr landed; 4 in flight
    } else {
      asm volatile("s_waitcnt vmcnt(0)" ::: "memory");
    }
    __builtin_amdgcn_sched_barrier(0);
    __builtin_amdgcn_s_barrier();   // staged tile visible to all waves

    const int kstart = (vt - 4) * 64;  // valid when !gph
    const int kg0 = vt * 64;           // valid when gph
    float sc[4][4];
    const bool full = !gph && (kstart + 63 <= iw) && (!is_local || kstart >= iw - 241);
    __builtin_amdgcn_s_setprio(1);     // T5: favor this wave's QK MFMAs
#pragma unroll
    for (int nt = 0; nt < 4; ++nt) {
      bf16x8 kF0 = *(const bf16x8*)&Ks[buf][(nt * 16 + ln) * 64 + s0k];
      bf16x8 kF1 = *(const bf16x8*)&Ks[buf][(nt * 16 + ln) * 64 + s1k];
      f32x4 c = (f32x4){0.f, 0.f, 0.f, 0.f};
      c = __builtin_amdgcn_mfma_f32_16x16x32_bf16(qA0, kF0, c, 0, 0, 0);
      c = __builtin_amdgcn_mfma_f32_16x16x32_bf16(qA1, kF1, c, 0, 0, 0);
      if (full) {
#pragma unroll
        for (int rg = 0; rg < 4; ++rg) sc[nt][rg] = c[rg] * S2 - B2;
      } else if (!gph) {
        int j = kstart + nt * 16 + ln;
#pragma unroll
        for (int rg = 0; rg < 4; ++rg) {
          int i = irow + rg;
          bool ok = is_local ? (j >= i - 256 && j <= i) : (j <= i);
          sc[nt][rg] = ok ? (c[rg] * S2 - B2) : -1e9f;
        }
      } else {
        int jg = gidx[kg0 + nt * 16 + ln];
#pragma unroll
        for (int rg = 0; rg < 4; ++rg) {
          bool ok = jg > (irow + rg);
          sc[nt][rg] = ok ? (c[rg] * S2 - B2) : -1e9f;
        }
      }
    }
    __builtin_amdgcn_s_setprio(0);     // exp/P-write phase at normal prio

    // P in its own buffer: each wave writes+reads only rows wave*16..+15 ->
    // no barrier (same-wave DS ordering).
    __bf16* P = (__bf16*)Ps;
#pragma unroll
    for (int rg = 0; rg < 4; ++rg) {
      int prow = wave * 16 + quad * 4 + rg;
      int pbase = prow * 64 + ln7;
      int pr7 = prow & 7;
#pragma unroll
      for (int nt = 0; nt < 4; ++nt)
        P[pbase + (((nt * 2 + lnh) ^ pr7) << 3)] = (__bf16)exp2f(sc[nt][rg]);
    }
    bf16x8 pF0 = *(const bf16x8*)&Ps[(wave * 16 + ln) * 64 + s0k];
    bf16x8 pF1 = *(const bf16x8*)&Ps[(wave * 16 + ln) * 64 + s1k];
    __builtin_amdgcn_s_setprio(1);     // T5: PV MFMA cluster
    ls = __builtin_amdgcn_mfma_f32_16x16x32_bf16(pF0, onesF, ls, 0, 0, 0);
    ls = __builtin_amdgcn_mfma_f32_16x16x32_bf16(pF1, onesF, ls, 0, 0, 0);
#pragma unroll
    for (int dt = 0; dt < 4; ++dt) {
      bf16x8 vF0 = *(const bf16x8*)&Vs[buf][(dt * 16 + ln) * 64 + s0k];
      bf16x8 vF1 = *(const bf16x8*)&Vs[buf][(dt * 16 + ln) * 64 + s1k];
      o[dt] = __builtin_amdgcn_mfma_f32_16x16x32_bf16(pF0, vF0, o[dt], 0, 0, 0);
      o[dt] = __builtin_amdgcn_mfma_f32_16x16x32_bf16(pF1, vF1, o[dt], 0, 0, 0);
    }
    __builtin_amdgcn_s_setprio(0);

    asm volatile("s_waitcnt lgkmcnt(0)" ::: "memory"); // buf reads done
    __builtin_amdgcn_sched_barrier(0);
    __builtin_amdgcn_s_barrier();                      // safe to overwrite buf
    buf ^= 1;
  }

  if (gid >= 1536 || !multi) {  // local + single-part global: direct write
#pragma unroll
    for (int dt = 0; dt < 4; ++dt)
#pragma unroll
      for (int rg = 0; rg < 4; ++rg) {
        int row = b * SQ + qb0 + wave * 16 + quad * 4 + rg;
        int e = h * 64 + dt * 16 + ln;
        AOut[(size_t)row * 768 + e] = bfbits(o[dt][rg] / ls[rg]);
      }
  } else {  // multi-part global: partials (slot == gid)
#pragma unroll
    for (int dt = 0; dt < 4; ++dt)
#pragma unroll
      for (int rg = 0; rg < 4; ++rg) {
        int row = wave * 16 + quad * 4 + rg;
        Opart[(size_t)gid * 4096 + row * 64 + dt * 16 + ln] = bfbits(o[dt][rg]);
      }
    if (ln == 0) {
#pragma unroll
      for (int rg = 0; rg < 4; ++rg)
        Lpart[(size_t)gid * 64 + wave * 16 + quad * 4 + rg] = ls[rg];
    }
  }
}

// ---------------- combine split-K partials (global heads, qb>=4) -----------
__global__ __launch_bounds__(256) void combine_parts(
    const unsigned short* __restrict__ Opart, const float* __restrict__ Lpart,
    unsigned short* __restrict__ AOut) {
  const int bid = blockIdx.x;        // 448 = 16 bh * 28 (qb 4..31)
  const int bh = bid / 28, qb = bid % 28 + 4;
  const int b = bh >> 2, h = 8 + (bh & 3);
  int C, np;
  if (qb < 12)      { C = 2 * qb - 4;  np = 2; }
  else if (qb < 20) { C = 3 * qb - 16; np = 3; }
  else if (qb < 28) { C = 4 * qb - 36; np = 4; }
  else              { C = 5 * qb - 64; np = 5; }
  const int slot0 = bh * 96 + C;
  const int t = threadIdx.x, r = t >> 2, c0 = (t & 3) * 16;
  float acc[16];
#pragma unroll
  for (int z = 0; z < 16; ++z) acc[z] = 0.f;
  float l = 0.f;
  for (int p = 0; p < np; ++p) {
    const unsigned short* src = &Opart[(size_t)(slot0 + p) * 4096 + r * 64 + c0];
    bf16x8 v0 = *(const bf16x8*)&src[0];
    bf16x8 v1 = *(const bf16x8*)&src[8];
#pragma unroll
    for (int z = 0; z < 8; ++z) { acc[z] += (float)v0[z]; acc[8 + z] += (float)v1[z]; }
    l += Lpart[(size_t)(slot0 + p) * 64 + r];
  }
  float inv = 1.f / l;
  unsigned short pk[16];
#pragma unroll
  for (int z = 0; z < 16; ++z) pk[z] = bfbits(acc[z] * inv);
  size_t dst = (size_t)(b * SQ + qb * 64 + r) * 768 + h * 64 + c0;
  *(uint4*)&AOut[dst]     = *(uint4*)&pk[0];
  *(uint4*)&AOut[dst + 8] = *(uint4*)&pk[8];
}

// ---------------- launch ----------------
extern "C" void kernel_launch(void* const* d_in, const int* in_sizes, int n_in,
                              void* d_out, int out_size, void* d_ws, size_t ws_size,
                              hipStream_t stream) {
  const float* x      = (const float*)d_in[0];
  const float* w_attn = (const float*)d_in[1];
  const float* b_attn = (const float*)d_in[2];
  const float* w_proj = (const float*)d_in[3];
  const float* b_proj = (const float*)d_in[4];
  float* out = (float*)d_out;

  char* ws = (char*)d_ws;
  size_t off = 0;
  auto alloc = [&](size_t bytes) {
    void* p = ws + off;
    off += (bytes + 255) & ~(size_t)255;
    return p;
  };
  unsigned short* xb     = (unsigned short*)alloc((size_t)8192 * 768 * 2);   // reused as attn buf
  unsigned short* wattnT = (unsigned short*)alloc((size_t)2304 * 768 * 2);
  unsigned short* wprojT = (unsigned short*)alloc((size_t)768 * 768 * 2);
  unsigned short* qkvb   = (unsigned short*)alloc((size_t)8192 * 2304 * 2);
  unsigned short* Vtb    = (unsigned short*)alloc((size_t)48 * 64 * 2048 * 2);
  unsigned short* Kgb    = (unsigned short*)alloc((size_t)16 * 256 * 64 * 2);
  unsigned short* VgTb   = (unsigned short*)alloc((size_t)16 * 64 * 256 * 2);
  int* gidxb             = (int*)alloc((size_t)256 * 4);
  unsigned short* Opartb = (unsigned short*)alloc((size_t)1536 * 4096 * 2);
  float* Lpartb          = (float*)alloc((size_t)1536 * 64 * 4);
  unsigned short* attnb  = xb;  // xb dead after qkv_gemm

  prep<<<dim3(512 + 72 * 24 + 24 * 24), dim3(256), 0, stream>>>(
      x, xb, w_attn, wattnT, w_proj, wprojT);
  qkv_gemm<<<dim3(1152), dim3(256), 0, stream>>>(xb, wattnT, b_attn, qkvb, Vtb);
  vprep<<<dim3(128), dim3(256), 0, stream>>>(qkvb, Vtb, Kgb, VgTb, gidxb);
  attn_kernel<<<dim3(2560), dim3(256), 0, stream>>>(qkvb, Vtb, Kgb, VgTb, gidxb,
                                                    attnb, Opartb, Lpartb);
  combine_parts<<<dim3(448), dim3(256), 0, stream>>>(Opartb, Lpartb, attnb);
  proj_gemm<<<dim3(384), dim3(256), 0, stream>>>(attnb, wprojT, b_proj, out);
}